// Round 10
// baseline (542.673 us; speedup 1.0000x reference)
//
#include <hip/hip_runtime.h>

typedef _Float16 f16;
typedef f16 f16x2 __attribute__((ext_vector_type(2)));
typedef f16 f16x8 __attribute__((ext_vector_type(8)));
typedef float f32x4 __attribute__((ext_vector_type(4)));
typedef float f32x2 __attribute__((ext_vector_type(2)));

#define MFMA16(a, b, c) __builtin_amdgcn_mfma_f32_16x16x32_f16((a), (b), (c), 0, 0, 0)

#define NBLK 256
#define NTHR 512

static __device__ __forceinline__ f16x8 cvt8(const float* __restrict__ p) {
    f32x4 p0 = *(const f32x4*)p;
    f32x4 p1 = *(const f32x4*)(p + 4);
    f16x8 a;
    a[0] = (f16)p0[0]; a[1] = (f16)p0[1]; a[2] = (f16)p0[2]; a[3] = (f16)p0[3];
    a[4] = (f16)p1[0]; a[5] = (f16)p1[1]; a[6] = (f16)p1[2]; a[7] = (f16)p1[3];
    return a;
}

// Grid barrier k: arrive-counter (self-resets to 0) + generation flag
// (monotonic within an iteration; memset re-zeros both between iterations).
// AGENT-scope acq/rel gives cross-XCD visibility (release flushes L2,
// acquire invalidates) — same mechanism as HIP cooperative grid.sync.
static __device__ __forceinline__ void gsync(unsigned* gb, int k) {
    __syncthreads();
    if (threadIdx.x == 0) {
        unsigned* cnt = gb + k * 64;
        unsigned* flag = gb + k * 64 + 32;
        unsigned gen = __hip_atomic_load(flag, __ATOMIC_RELAXED, __HIP_MEMORY_SCOPE_AGENT);
        unsigned old = __hip_atomic_fetch_add(cnt, 1u, __ATOMIC_ACQ_REL, __HIP_MEMORY_SCOPE_AGENT);
        if (old == NBLK - 1u) {
            __hip_atomic_store(cnt, 0u, __ATOMIC_RELAXED, __HIP_MEMORY_SCOPE_AGENT);
            __hip_atomic_fetch_add(flag, 1u, __ATOMIC_RELEASE, __HIP_MEMORY_SCOPE_AGENT);
        } else {
            while (__hip_atomic_load(flag, __ATOMIC_ACQUIRE, __HIP_MEMORY_SCOPE_AGENT) == gen)
                __builtin_amdgcn_s_sleep(2);
        }
    }
    __syncthreads();
}

// ONE persistent kernel: prep -> scan -> scat+proj -> depth 0..3.
// All compute bodies verbatim from the proven v7 kernels (345.7 us run);
// only the dispatch boundaries are replaced by grid barriers.
__global__ __launch_bounds__(512) void k_all(
        const float* __restrict__ x, const int* __restrict__ ei,
        const float* __restrict__ eattr, const int* __restrict__ dep,
        const float* __restrict__ pw, const float* __restrict__ pb,
        const float* __restrict__ mw1, const float* __restrict__ mb1,
        const float* __restrict__ mw2, const float* __restrict__ mb2,
        const float* __restrict__ uw1, const float* __restrict__ ub1,
        const float* __restrict__ uw2, const float* __restrict__ ub2,
        float* __restrict__ h, f16* __restrict__ tOrg, f16* __restrict__ hh,
        f16* __restrict__ tUpd, unsigned* gb, int* degv, int* cur, int* dcnt,
        int* rowp, int* bsum, int2* esea, int4* recs,
        f16* pwp, f16* mw1p, f16* mw2p, f16* uw1p, f16* uw2p,
        int N, int E) {
    __shared__ __align__(16) f16 bsm[128 * 128];     // 32 KB staged mw2p
    __shared__ __align__(16) f16 tbuf[8][16][136];   // 34 KB: msg rows / proj lds
    __shared__ __align__(16) f16 pool[16][136];
    __shared__ __align__(16) f16 sout[16][136];
    __shared__ int2 ebuf[8][16];
    __shared__ int ids[16], se0[16], se1[16];
    __shared__ int sarr[512];                        // scan scratch
    __shared__ int lcnt[4], lbase[4];

    const int tid = threadIdx.x;
    const int lane = tid & 63;
    const int w = tid >> 6;                  // wave 0..7
    const int colx = lane & 15, quad = lane >> 4;
    const int b = blockIdx.x;
    const int gtid = b * NTHR + tid;
    const int gsz = NBLK * NTHR;

    // ================= P0: prep (repack / classify / deg count) =============
    if (b < 24) {
        int item = b * 512 + tid;            // 48 weight-blocks x 256
        int wb = item >> 8;
        int t8 = item & 255;
        const float* W; f16* out; int fb;
        if (wb < 8)       { W = pw;  out = pwp;  fb = wb; }
        else if (wb < 16) { W = mw1; out = mw1p; fb = wb - 8; }
        else if (wb < 24) { W = mw2; out = mw2p; fb = wb - 16; }
        else if (wb < 40) { W = uw1; out = uw1p; fb = wb - 24; }
        else              { W = uw2; out = uw2p; fb = wb - 40; }
        int idx = fb * 256 + t8;
        int lane2 = idx & 63;
        int nt = (idx >> 6) & 7;
        int kt = idx >> 9;
        int cx = lane2 & 15, qd = lane2 >> 4;
        f16* o = out + (size_t)idx * 8;
        const float* wbp = W + (size_t)(kt * 32 + qd * 8) * 128 + nt * 16 + cx;
#pragma unroll
        for (int j = 0; j < 8; j++) o[j] = (f16)wbp[(size_t)j * 128];
    } else {
        int NCB = (N + 511) >> 9;
        int cb = b - 24;
        if (cb < NCB) {
            if (tid < 4) lcnt[tid] = 0;
            __syncthreads();
            int v = cb * 512 + tid;
            int d = (v < N) ? dep[v] : 0;
            int p = -1;
            if (d >= 1 && d <= 4) p = atomicAdd(&lcnt[d - 1], 1);
            __syncthreads();
            if (tid < 4) lbase[tid] = (lcnt[tid] > 0) ? atomicAdd(&dcnt[tid], lcnt[tid]) : 0;
            __syncthreads();
            if (d >= 1 && d <= 4) recs[(size_t)(d - 1) * N + lbase[d - 1] + p].x = v;
        }
    }
    for (int e = gtid; e < E; e += gsz) atomicAdd(&degv[ei[E + e]], 1);
    gsync(gb, 0);

    // ================= P1a: per-block degv segment sums ======================
    const int SEG = (N + NBLK - 1) / NBLK;   // <= 512 for N <= 131072
    {
        int i = b * SEG + tid;
        int v = (tid < SEG && i < N) ? degv[i] : 0;
        sarr[tid] = v;
        __syncthreads();
#pragma unroll
        for (int s = 256; s > 0; s >>= 1) {
            if (tid < s) sarr[tid] += sarr[tid + s];
            __syncthreads();
        }
        if (tid == 0) bsum[b] = sarr[0];
    }
    gsync(gb, 1);

    // ================= P1b: rowp via two-level scan ==========================
    {
        int bsumb = bsum[b];
        sarr[tid] = (tid < NBLK) ? bsum[tid] : 0;
        __syncthreads();
#pragma unroll
        for (int d = 1; d < 512; d <<= 1) {
            int u = (tid >= d) ? sarr[tid - d] : 0;
            __syncthreads();
            sarr[tid] += u;
            __syncthreads();
        }
        int base = sarr[b] - bsumb;          // exclusive block prefix
        __syncthreads();
        int i = b * SEG + tid;
        int v = (tid < SEG && i < N) ? degv[i] : 0;
        sarr[tid] = v;
        __syncthreads();
#pragma unroll
        for (int d = 1; d < 512; d <<= 1) {
            int u = (tid >= d) ? sarr[tid - d] : 0;
            __syncthreads();
            sarr[tid] += u;
            __syncthreads();
        }
        if (tid < SEG && i < N) rowp[i] = base + sarr[tid] - v;
        if (b == 0 && tid == 0) rowp[N] = E;
    }
    gsync(gb, 2);

    // ================= P2: scat  +  P3: proj GEMM ============================
    for (int e = gtid; e < E; e += gsz) {
        int s = ei[e], dn = ei[E + e];
        int p = rowp[dn] + atomicAdd(&cur[dn], 1);
        esea[p] = (int2){s | (dep[s] << 20), __float_as_int(eattr[e])};
    }
    for (int d4 = 0; d4 < 4; d4++) {
        int cntd = dcnt[d4];
        for (int i = gtid; i < cntd; i += gsz) {
            int4* r = &recs[(size_t)d4 * N + i];
            int u = r->x;
            r->y = rowp[u];
            r->z = rowp[u + 1];
        }
    }
    {
        f16* plds = &tbuf[w][0][0];          // per-wave 16x136 scratch
        int ntile = (N + 15) >> 4;
        for (int tile = b * 8 + w; tile < ntile; tile += NBLK * 8) {
            int base = tile * 16;
            int arow = base + colx;
            int u = arow < N ? arow : N - 1;
            f32x4 c1[8];
#pragma unroll
            for (int nt = 0; nt < 8; nt++) c1[nt] = (f32x4){0.f, 0.f, 0.f, 0.f};
#pragma unroll
            for (int kt = 0; kt < 4; kt++) {
                f16x8 a = cvt8(x + (size_t)u * 128 + kt * 32 + quad * 8);
#pragma unroll
                for (int nt = 0; nt < 8; nt++) {
                    f16x8 bb = *(const f16x8*)(pwp + ((size_t)(kt * 8 + nt) * 64 + lane) * 8);
                    c1[nt] = MFMA16(a, bb, c1[nt]);
                }
            }
#pragma unroll
            for (int nt = 0; nt < 8; nt++) {
                float bias = pb[nt * 16 + colx];
#pragma unroll
                for (int reg = 0; reg < 4; reg++) {
                    int row = quad * 4 + reg;
                    int node = base + row;
                    float v = c1[nt][reg] + bias;
                    plds[row * 136 + nt * 16 + colx] = (f16)v;
                    if (node < N) {
                        h[(size_t)node * 128 + nt * 16 + colx] = v;
                        hh[(size_t)node * 128 + nt * 16 + colx] = (f16)v;
                    }
                }
            }
            f32x4 c2[8];
#pragma unroll
            for (int nt = 0; nt < 8; nt++) c2[nt] = (f32x4){0.f, 0.f, 0.f, 0.f};
#pragma unroll
            for (int kt = 0; kt < 4; kt++) {
                f16x8 a = *(const f16x8*)&plds[colx * 136 + kt * 32 + quad * 8];
#pragma unroll
                for (int nt = 0; nt < 8; nt++) {
                    f16x8 bb = *(const f16x8*)(mw1p + ((size_t)(kt * 8 + nt) * 64 + lane) * 8);
                    c2[nt] = MFMA16(a, bb, c2[nt]);
                }
            }
#pragma unroll
            for (int nt = 0; nt < 8; nt++) {
                float bias = mb1[nt * 16 + colx];
#pragma unroll
                for (int reg = 0; reg < 4; reg++) {
                    int node = base + quad * 4 + reg;
                    if (node < N)
                        tOrg[(size_t)node * 128 + nt * 16 + colx] = (f16)(c2[nt][reg] + bias);
                }
            }
        }
    }
    gsync(gb, 3);

    // ================= depth loop (v7 k_md body, dIdx = dI) ==================
    {
        const f16x8* s8 = (const f16x8*)mw2p;
        f16x8* d8 = (f16x8*)bsm;
#pragma unroll
        for (int i = 0; i < 4; i++) d8[i * 512 + tid] = s8[i * 512 + tid];
    }
    const float* w1r = mw1 + 128 * 128;
    f16x8 w1h[4];
#pragma unroll
    for (int kt = 0; kt < 4; kt++) {
        f32x4 q0 = *(const f32x4*)(w1r + kt * 32 + quad * 8);
        f32x4 q1 = *(const f32x4*)(w1r + kt * 32 + quad * 8 + 4);
        w1h[kt][0] = (f16)q0[0]; w1h[kt][1] = (f16)q0[1];
        w1h[kt][2] = (f16)q0[2]; w1h[kt][3] = (f16)q0[3];
        w1h[kt][4] = (f16)q1[0]; w1h[kt][5] = (f16)q1[1];
        w1h[kt][6] = (f16)q1[2]; w1h[kt][7] = (f16)q1[3];
    }
    float mb2v[8];
#pragma unroll
    for (int nt = 0; nt < 8; nt++) mb2v[nt] = mb2[nt * 16 + colx];
    f16* hbuf = &tbuf[0][0][0];
    __syncthreads();  // bsm ready

    for (int dI = 0; dI < 4; dI++) {
        const int cnt = dcnt[dI];
        const int s0 = (int)((long long)cnt * b / NBLK);
        const int s1 = (int)((long long)cnt * (b + 1) / NBLK);
        auto srow = [&](int sv) -> const f16* {
            const f16* tb = ((unsigned)((sv >> 20) - 1) < (unsigned)dI) ? tUpd : tOrg;
            return tb + (size_t)(sv & 0xFFFFF) * 128;
        };

        for (int cs = s0; cs < s1; cs += 16) {
            int cc = s1 - cs; if (cc > 16) cc = 16;
            if (tid < 16) {
                if (tid < cc) {
                    int4 r = recs[(size_t)dI * N + cs + tid];
                    ids[tid] = r.x; se0[tid] = r.y; se1[tid] = r.z;
                } else {
                    ids[tid] = 0; se0[tid] = 0; se1[tid] = 0;
                }
            }
            __syncthreads();

            // msg phase: 2 groups of 8 nodes
            for (int g = 0; g < 2; g++) {
                int maxT = 0;
#pragma unroll
                for (int s = 0; s < 8; s++) {
                    int r = g * 8 + s;
                    int tc = (se1[r] - se0[r] + 15) >> 4;
                    if (tc > maxT) maxT = tc;
                }
                float aggv[8] = {0.f, 0.f, 0.f, 0.f, 0.f, 0.f, 0.f, 0.f};
                for (int rd = 0; rd < maxT; rd++) {
                    if (tid < 128) {
                        int s = tid >> 4, j = tid & 15;
                        int r = g * 8 + s;
                        int es = se0[r] + rd * 16 + j;
                        if (es < se1[r]) ebuf[s][j] = esea[es];
                    }
                    __syncthreads();
#pragma unroll
                    for (int it = 0; it < 4; it++) {
                        int task = it * 512 + tid;
                        int row = task >> 4, seg = task & 15;
                        int s = row >> 4, j = row & 15;
                        int r = g * 8 + s;
                        int es = se0[r] + rd * 16 + j;
                        if (es < se1[r]) {
                            int sv = ebuf[s][j].x;
                            *(f16x8*)&tbuf[s][j][seg * 8] =
                                *(const f16x8*)(srow(sv) + seg * 8);
                        }
                    }
                    __syncthreads();
                    {
                        int r = g * 8 + w;
                        int bs = se0[r] + rd * 16;
                        int rem = se1[r] - bs;
                        if (rem > 0) {
                            f16 eah = (f16)__int_as_float(ebuf[w][colx].y);
                            f16x8 afr[4];
#pragma unroll
                            for (int kt = 0; kt < 4; kt++) {
                                f16x8 v = *(const f16x8*)&tbuf[w][colx][kt * 32 + quad * 8];
                                f16x8 o;
#pragma unroll
                                for (int j2 = 0; j2 < 8; j2++) {
                                    f16 qv = v[j2] + eah * w1h[kt][j2];
                                    o[j2] = qv > (f16)0 ? qv : (f16)0;
                                }
                                afr[kt] = o;
                            }
#pragma unroll
                            for (int nt = 0; nt < 8; nt++) {
                                f32x4 c = (f32x4){0.f, 0.f, 0.f, 0.f};
#pragma unroll
                                for (int kt = 0; kt < 4; kt++) {
                                    f16x8 bb = *(const f16x8*)&bsm[((kt * 8 + nt) * 64 + lane) * 8];
                                    c = MFMA16(afr[kt], bb, c);
                                }
#pragma unroll
                                for (int reg = 0; reg < 4; reg++)
                                    if (quad * 4 + reg < rem)
                                        aggv[nt] += fmaxf(c[reg] + mb2v[nt], 0.f);
                            }
                        }
                    }
                    __syncthreads();
                }
                {
                    int r = g * 8 + w;
                    int deg = se1[r] - se0[r];
                    float inv = 1.f / (float)(deg > 1 ? deg : 1);
#pragma unroll
                    for (int nt = 0; nt < 8; nt++) {
                        float s = aggv[nt];
                        s += __shfl_xor(s, 16, 64);
                        s += __shfl_xor(s, 32, 64);
                        if (quad == 0) pool[r][nt * 16 + colx] = (f16)(s * inv);
                    }
                }
            }
            __syncthreads();

            if (tid < 256) {
                int row = tid >> 4, seg = tid & 15;
                *(f16x8*)&hbuf[row * 136 + seg * 8] =
                    *(const f16x8*)(hh + (size_t)ids[row] * 128 + seg * 8);
            }
            __syncthreads();

            // update phase: wave w owns nt = w
            f32x4 c1 = (f32x4){0.f, 0.f, 0.f, 0.f};
#pragma unroll
            for (int kt = 0; kt < 8; kt++) {
                f16x8 a;
                if (kt < 4)
                    a = *(const f16x8*)&hbuf[colx * 136 + kt * 32 + quad * 8];
                else
                    a = *(const f16x8*)&pool[colx][(kt - 4) * 32 + quad * 8];
                f16x8 bb = *(const f16x8*)(uw1p + ((size_t)(kt * 8 + w) * 64 + lane) * 8);
                c1 = MFMA16(a, bb, c1);
            }
            {
                float bias = ub1[w * 16 + colx];
#pragma unroll
                for (int reg = 0; reg < 4; reg++) {
                    int row = quad * 4 + reg;
                    sout[row][w * 16 + colx] = (f16)fmaxf(c1[reg] + bias, 0.f);
                }
            }
            __syncthreads();
            f32x4 c2 = (f32x4){0.f, 0.f, 0.f, 0.f};
#pragma unroll
            for (int kt = 0; kt < 4; kt++) {
                f16x8 a = *(const f16x8*)&sout[colx][kt * 32 + quad * 8];
                f16x8 bb = *(const f16x8*)(uw2p + ((size_t)(kt * 8 + w) * 64 + lane) * 8);
                c2 = MFMA16(a, bb, c2);
            }
            {
                float bias = ub2[w * 16 + colx];
#pragma unroll
                for (int reg = 0; reg < 4; reg++) {
                    int row = quad * 4 + reg;
                    float v = fmaxf(c2[reg] + bias, 0.f);
                    pool[row][w * 16 + colx] = (f16)v;
                    if (row < cc)
                        h[(size_t)ids[row] * 128 + w * 16 + colx] = v;
                }
            }
            __syncthreads();
            if (dI < 3) {
                f32x4 c3 = (f32x4){0.f, 0.f, 0.f, 0.f};
#pragma unroll
                for (int kt = 0; kt < 4; kt++) {
                    f16x8 a = *(const f16x8*)&pool[colx][kt * 32 + quad * 8];
                    f16x8 bb = *(const f16x8*)(mw1p + ((size_t)(kt * 8 + w) * 64 + lane) * 8);
                    c3 = MFMA16(a, bb, c3);
                }
                float bias = mb1[w * 16 + colx];
#pragma unroll
                for (int reg = 0; reg < 4; reg++) {
                    int row = quad * 4 + reg;
                    if (row < cc)
                        tUpd[(size_t)ids[row] * 128 + w * 16 + colx] =
                            (f16)(c3[reg] + bias);
                }
            }
            __syncthreads();
        }
        if (dI < 3) gsync(gb, 4 + dI);
    }
}

extern "C" void kernel_launch(void* const* d_in, const int* in_sizes, int n_in,
                              void* d_out, int out_size, void* d_ws, size_t ws_size,
                              hipStream_t stream) {
    const float* x    = (const float*)d_in[0];
    const int*   ei   = (const int*)d_in[1];
    const float* eatt = (const float*)d_in[2];
    const int*   dep  = (const int*)d_in[3];
    const float* pw   = (const float*)d_in[4];
    const float* pb   = (const float*)d_in[5];
    const float* mw1  = (const float*)d_in[6];
    const float* mb1  = (const float*)d_in[7];
    const float* mw2  = (const float*)d_in[8];
    const float* mb2  = (const float*)d_in[9];
    const float* uw1  = (const float*)d_in[10];
    const float* ub1  = (const float*)d_in[11];
    const float* uw2  = (const float*)d_in[12];
    const float* ub2  = (const float*)d_in[13];
    float* h = (float*)d_out;

    int N = in_sizes[3];
    int E = in_sizes[1] / 2;

    char* ws = (char*)d_ws;
    size_t o = 0;
    auto alloc = [&](size_t bytes) -> char* {
        char* p = ws + o;
        o += (bytes + 255) & ~(size_t)255;
        return p;
    };
    f16*   t    = (f16*)alloc((size_t)N * 128 * 2);   // tOrg
    f16*   hh   = (f16*)alloc((size_t)N * 128 * 2);
    f16*   tUpd = (f16*)alloc((size_t)N * 128 * 2);
    char*  z0   = (char*)alloc(0);
    unsigned* gbarr = (unsigned*)alloc(8 * 64 * 4);   // 8 barrier pairs
    int*   degv = (int*)alloc((size_t)N * 4);
    int*   cur  = (int*)alloc((size_t)N * 4);
    int*   dcnt = (int*)alloc(64);
    size_t zbytes = (size_t)((char*)alloc(0) - z0);
    int*   rowp = (int*)alloc((size_t)(N + 1) * 4);
    int*   bsum = (int*)alloc((size_t)NBLK * 4);
    int2*  esea = (int2*)alloc((size_t)E * 8);
    int4*  recs = (int4*)alloc((size_t)4 * N * 16);
    f16*   pwp  = (f16*)alloc(128 * 128 * 2);
    f16*   mw1p = (f16*)alloc(128 * 128 * 2);
    f16*   mw2p = (f16*)alloc(128 * 128 * 2);
    f16*   uw1p = (f16*)alloc(256 * 128 * 2);
    f16*   uw2p = (f16*)alloc(128 * 128 * 2);

    hipMemsetAsync(z0, 0, zbytes, stream);

    k_all<<<NBLK, NTHR, 0, stream>>>(x, ei, eatt, dep, pw, pb, mw1, mb1,
                                     mw2, mb2, uw1, ub1, uw2, ub2,
                                     h, t, hh, tUpd, gbarr, degv, cur, dcnt,
                                     rowp, bsum, esea, recs,
                                     pwp, mw1p, mw2p, uw1p, uw2p, N, E);
}